// Round 1
// baseline (391.364 us; speedup 1.0000x reference)
//
#include <hip/hip_runtime.h>
#include <hip/hip_bf16.h>

// Problem constants
#define B_ 4
#define S_ 2048
#define D_ 1024
#define H_ 16
#define HD_ 64
#define M_ 8192           // B*S
#define NEGV -1000000.0f
#define LOG2E 1.44269504088896340736f

typedef __attribute__((ext_vector_type(8))) __bf16 bf16x8;
typedef __attribute__((ext_vector_type(4))) float f32x4;

__device__ __forceinline__ f32x4 mfma16(bf16x8 a, bf16x8 b, f32x4 c) {
  return __builtin_amdgcn_mfma_f32_16x16x32_bf16(a, b, c, 0, 0, 0);
}

// async global->LDS, 16B per lane. LDS dest must be wave-uniform base (HW adds lane*16).
__device__ __forceinline__ void gld_lds16(const __hip_bfloat16* g, __hip_bfloat16* l) {
  __builtin_amdgcn_global_load_lds(
      (const __attribute__((address_space(1))) void*)g,
      (__attribute__((address_space(3))) void*)l, 16, 0, 0);
}

// ---------------- fp32 -> bf16 elementwise convert (vectorized) ----------------
__global__ __launch_bounds__(256) void convert_x(const float* __restrict__ X,
                                                 __hip_bfloat16* __restrict__ Y, int n4) {
  int i = blockIdx.x * blockDim.x + threadIdx.x;
  if (i >= n4) return;
  float4 v = reinterpret_cast<const float4*>(X)[i];
  union { __hip_bfloat16 h[4]; ushort4 u; } cv;
  cv.h[0] = __float2bfloat16(v.x);
  cv.h[1] = __float2bfloat16(v.y);
  cv.h[2] = __float2bfloat16(v.z);
  cv.h[3] = __float2bfloat16(v.w);
  reinterpret_cast<ushort4*>(Y)[i] = cv.u;
}

// ---------------- W[1024][1024] fp32 -> W^T bf16 ----------------
__global__ __launch_bounds__(256) void convert_wt(const float* __restrict__ W,
                                                  __hip_bfloat16* __restrict__ Wt) {
  __shared__ float tile[32][33];
  int c0 = blockIdx.x * 32, r0 = blockIdx.y * 32;
  int tx = threadIdx.x, ty = threadIdx.y;
#pragma unroll
  for (int rr = ty; rr < 32; rr += 8)
    tile[rr][tx] = W[(size_t)(r0 + rr) * D_ + c0 + tx];
  __syncthreads();
#pragma unroll
  for (int rr = ty; rr < 32; rr += 8)
    Wt[(size_t)(c0 + rr) * D_ + r0 + tx] = __float2bfloat16(tile[tx][rr]);
}

// ---------------- GEMM: C[M,N] = A[M,K] * Bt[N,K]^T  (bf16 in, templated epilogue) ----
// EPI 0: bf16 out scattered to [B][H][S][HD]   (Q, K projections)
// EPI 1: bf16 out scattered to [B][H][HD][S]   (V^T projection)
// EPI 2: fp32 out row-major [M][N]             (final @ Wo)
template <int EPI>
__global__ __launch_bounds__(256) void gemm_bt(const __hip_bfloat16* __restrict__ A,
                                               const __hip_bfloat16* __restrict__ Bt,
                                               void* __restrict__ Cout) {
  const int t = threadIdx.x, lane = t & 63, wid = t >> 6;
  const int lc = lane & 15, g = lane >> 4;
  const int m0 = blockIdx.x * 128, n0 = blockIdx.y * 128;
  __shared__ __align__(16) __hip_bfloat16 As[128 * 32];
  __shared__ __align__(16) __hip_bfloat16 Bs[128 * 32];
  f32x4 acc[4][4] = {};
  const int wm = (wid & 1) * 64, wn = (wid >> 1) * 64;
  const int srow = lane >> 2;  // 0..15 (row within a 16-row staging chunk)
  const int sg = lane & 3;     // 16B granule within 64B row

  for (int k0 = 0; k0 < D_; k0 += 32) {
#pragma unroll
    for (int c = 0; c < 2; ++c) {
      int row = c * 64 + wid * 16 + srow;
      gld_lds16(A + (size_t)(m0 + row) * D_ + k0 + sg * 8, As + (c * 64 + wid * 16) * 32);
      gld_lds16(Bt + (size_t)(n0 + row) * D_ + k0 + sg * 8, Bs + (c * 64 + wid * 16) * 32);
    }
    __syncthreads();
    bf16x8 af[4], bf[4];
#pragma unroll
    for (int mi = 0; mi < 4; ++mi)
      af[mi] = *reinterpret_cast<const bf16x8*>(As + (wm + mi * 16 + lc) * 32 + g * 8);
#pragma unroll
    for (int ni = 0; ni < 4; ++ni)
      bf[ni] = *reinterpret_cast<const bf16x8*>(Bs + (wn + ni * 16 + lc) * 32 + g * 8);
#pragma unroll
    for (int mi = 0; mi < 4; ++mi)
#pragma unroll
      for (int ni = 0; ni < 4; ++ni)
        acc[mi][ni] = mfma16(af[mi], bf[ni], acc[mi][ni]);
    __syncthreads();
  }

#pragma unroll
  for (int mi = 0; mi < 4; ++mi) {
#pragma unroll
    for (int ni = 0; ni < 4; ++ni) {
#pragma unroll
      for (int i = 0; i < 4; ++i) {
        int gm = m0 + wm + mi * 16 + g * 4 + i;
        int gn = n0 + wn + ni * 16 + lc;
        float val = acc[mi][ni][i];
        if constexpr (EPI == 0) {
          int b = gm >> 11, s = gm & 2047, h = gn >> 6, d = gn & 63;
          ((__hip_bfloat16*)Cout)[(((size_t)(b * H_ + h) * S_ + s) << 6) + d] =
              __float2bfloat16(val);
        } else if constexpr (EPI == 1) {
          int b = gm >> 11, s = gm & 2047, h = gn >> 6, d = gn & 63;
          ((__hip_bfloat16*)Cout)[(((size_t)(b * H_ + h) * HD_ + d) << 11) + s] =
              __float2bfloat16(val);
        } else {
          ((float*)Cout)[(size_t)gm * D_ + gn] = val;
        }
      }
    }
  }
}

// ---------------- Flash attention ----------------
// grid: (S/64, B*H). Block = 4 waves; wave w owns 16 q-rows. KV tiles of 64.
// K_lds/V_lds/P_lds are XOR-swizzled (granule ^= row&7) -> conflict-free ds_read_b128.
// global_load_lds writes linearly, so the swizzle is applied to the GLOBAL source addr.
__global__ __launch_bounds__(256) void attn(const __hip_bfloat16* __restrict__ Qh,
                                            const __hip_bfloat16* __restrict__ Kh,
                                            const __hip_bfloat16* __restrict__ Vt,
                                            const int* __restrict__ vlens,
                                            __hip_bfloat16* __restrict__ O) {
  const int qt = blockIdx.x, bh = blockIdx.y;
  const int b = bh >> 4, h = bh & 15;
  const int t = threadIdx.x, lane = t & 63, w = t >> 6;
  const int lc = lane & 15, g = lane >> 4;
  const int vlen = vlens[b];

  __shared__ __align__(16) __hip_bfloat16 Ks[64 * 64];
  __shared__ __align__(16) __hip_bfloat16 Vs[64 * 64];
  __shared__ __align__(16) __hip_bfloat16 Ps[4][16 * 64];

  const __hip_bfloat16* Qb = Qh + (size_t)bh * S_ * HD_;
  const __hip_bfloat16* Kb = Kh + (size_t)bh * S_ * HD_;
  const __hip_bfloat16* Vb = Vt + (size_t)bh * HD_ * S_;

  const int q0 = qt * 64;
  const int qrow = q0 + w * 16 + lc;  // A-frag row = lane&15
  bf16x8 qf[2];
  qf[0] = *reinterpret_cast<const bf16x8*>(Qb + (size_t)qrow * HD_ + g * 8);
  qf[1] = *reinterpret_cast<const bf16x8*>(Qb + (size_t)qrow * HD_ + 32 + g * 8);

  f32x4 acc_o[4] = {};
  float m_i[4], l_i[4];
#pragma unroll
  for (int i = 0; i < 4; ++i) { m_i[i] = -__builtin_inff(); l_i[i] = 0.f; }

  const int srow8 = lane >> 3;  // 0..7
  const int sg8 = lane & 7;     // 16B granule within 128B row

  for (int kv = 0; kv < S_; kv += 64) {
    // stage K tile [64 keys][64 d] and V^T tile [64 d][64 keys], swizzled source
#pragma unroll
    for (int c = 0; c < 2; ++c) {
      int row = w * 16 + c * 8 + srow8;
      int gsw = sg8 ^ (row & 7);
      gld_lds16(Kb + (size_t)(kv + row) * HD_ + gsw * 8, Ks + (w * 16 + c * 8) * 64);
      gld_lds16(Vb + (size_t)row * S_ + kv + gsw * 8, Vs + (w * 16 + c * 8) * 64);
    }
    __syncthreads();

    // S-tile: rows = q (g*4+i), cols = key (ct*16+lc)
    float sc[4][4];
#pragma unroll
    for (int ct = 0; ct < 4; ++ct) {
      f32x4 a = {};
#pragma unroll
      for (int kk = 0; kk < 2; ++kk) {
        int row = ct * 16 + lc;
        int gp = (kk * 4 + g) ^ (row & 7);
        bf16x8 kf = *reinterpret_cast<const bf16x8*>(Ks + row * 64 + gp * 8);
        a = mfma16(qf[kk], kf, a);
      }
      int j = kv + ct * 16 + lc;
      bool valid = j < vlen;
#pragma unroll
      for (int i = 0; i < 4; ++i) sc[ct][i] = valid ? a[i] * 0.125f : NEGV;
    }

    // online softmax (rows live across 16 lanes sharing g)
    float pv[4][4];
#pragma unroll
    for (int i = 0; i < 4; ++i) {
      float mn = fmaxf(fmaxf(sc[0][i], sc[1][i]), fmaxf(sc[2][i], sc[3][i]));
#pragma unroll
      for (int off = 1; off < 16; off <<= 1) mn = fmaxf(mn, __shfl_xor(mn, off));
      float mt = fmaxf(m_i[i], mn);
      float alpha = exp2f((m_i[i] - mt) * LOG2E);
      m_i[i] = mt;
      float rs = 0.f;
#pragma unroll
      for (int ct = 0; ct < 4; ++ct) {
        float p = exp2f((sc[ct][i] - mt) * LOG2E);
        pv[ct][i] = p;
        rs += p;
      }
#pragma unroll
      for (int off = 1; off < 16; off <<= 1) rs += __shfl_xor(rs, off);
      l_i[i] = l_i[i] * alpha + rs;
#pragma unroll
      for (int ctd = 0; ctd < 4; ++ctd) acc_o[ctd][i] *= alpha;
    }

    // P -> LDS (per-wave region, same XOR swizzle)
#pragma unroll
    for (int ct = 0; ct < 4; ++ct) {
      int col = ct * 16 + lc;
      int gr = col >> 3, rem = col & 7;
#pragma unroll
      for (int i = 0; i < 4; ++i) {
        int prow = g * 4 + i;
        Ps[w][prow * 64 + ((gr ^ (prow & 7)) << 3) + rem] = __float2bfloat16(pv[ct][i]);
      }
    }
    __syncthreads();

    // PV: A = P[q=lc][k], B = V[k][d] from Vs[d=lc-col][k]
#pragma unroll
    for (int ctd = 0; ctd < 4; ++ctd) {
#pragma unroll
      for (int kk = 0; kk < 2; ++kk) {
        int gp = (kk * 4 + g) ^ (lc & 7);
        bf16x8 pf = *reinterpret_cast<const bf16x8*>(&Ps[w][lc * 64 + gp * 8]);
        int vrow = ctd * 16 + lc;
        int vgp = (kk * 4 + g) ^ (vrow & 7);
        bf16x8 vf = *reinterpret_cast<const bf16x8*>(Vs + vrow * 64 + vgp * 8);
        acc_o[ctd] = mfma16(pf, vf, acc_o[ctd]);
      }
    }
    __syncthreads();
  }

  // epilogue: O[b][s][h*64+d] bf16 (merged heads)
#pragma unroll
  for (int i = 0; i < 4; ++i) {
    float inv = 1.0f / l_i[i];
    int s = q0 + w * 16 + g * 4 + i;
    size_t base = ((size_t)b * S_ + s) * D_ + h * HD_;
#pragma unroll
    for (int ctd = 0; ctd < 4; ++ctd)
      O[base + ctd * 16 + lc] = __float2bfloat16(acc_o[ctd][i] * inv);
  }
}

extern "C" void kernel_launch(void* const* d_in, const int* in_sizes, int n_in,
                              void* d_out, int out_size, void* d_ws, size_t ws_size,
                              hipStream_t stream) {
  const float* Xq = (const float*)d_in[0];
  const float* Xk = (const float*)d_in[1];
  const float* Xv = (const float*)d_in[2];
  const int* vl = (const int*)d_in[3];
  const float* Wq = (const float*)d_in[4];
  const float* Wk = (const float*)d_in[5];
  const float* Wv = (const float*)d_in[6];
  const float* Wo = (const float*)d_in[7];
  float* out = (float*)d_out;

  char* ws = (char*)d_ws;
  const size_t XB = (size_t)M_ * D_ * 2;   // 16 MB bf16 [8192][1024]
  const size_t WB = (size_t)D_ * D_ * 2;   // 2 MB bf16 [1024][1024]
  __hip_bfloat16* xb = (__hip_bfloat16*)(ws);                 // X bf16 (reused), later O
  __hip_bfloat16* wtq = (__hip_bfloat16*)(ws + XB);
  __hip_bfloat16* wtk = (__hip_bfloat16*)(ws + XB + WB);
  __hip_bfloat16* wtv = (__hip_bfloat16*)(ws + XB + 2 * WB);
  __hip_bfloat16* wto = (__hip_bfloat16*)(ws + XB + 3 * WB);
  __hip_bfloat16* Qh = (__hip_bfloat16*)(ws + XB + 4 * WB);           // [B][H][S][HD]
  __hip_bfloat16* Kh = (__hip_bfloat16*)(ws + 2 * XB + 4 * WB);       // [B][H][S][HD]
  __hip_bfloat16* Vh = (__hip_bfloat16*)(ws + 3 * XB + 4 * WB);       // [B][H][HD][S]
  __hip_bfloat16* Obuf = xb;  // alias: X buffer is dead after the V projection

  dim3 tg(32, 32), tb(32, 8);
  convert_wt<<<tg, tb, 0, stream>>>(Wq, wtq);
  convert_wt<<<tg, tb, 0, stream>>>(Wk, wtk);
  convert_wt<<<tg, tb, 0, stream>>>(Wv, wtv);
  convert_wt<<<tg, tb, 0, stream>>>(Wo, wto);

  const int n4 = M_ * D_ / 4;
  dim3 gg(M_ / 128, D_ / 128);
  convert_x<<<n4 / 256, 256, 0, stream>>>(Xq, xb, n4);
  gemm_bt<0><<<gg, 256, 0, stream>>>(xb, wtq, Qh);
  convert_x<<<n4 / 256, 256, 0, stream>>>(Xk, xb, n4);
  gemm_bt<0><<<gg, 256, 0, stream>>>(xb, wtk, Kh);
  convert_x<<<n4 / 256, 256, 0, stream>>>(Xv, xb, n4);
  gemm_bt<1><<<gg, 256, 0, stream>>>(xb, wtv, Vh);

  attn<<<dim3(S_ / 64, B_ * H_), 256, 0, stream>>>(Qh, Kh, Vh, vl, Obuf);
  gemm_bt<2><<<gg, 256, 0, stream>>>(Obuf, wto, out);
}

// Round 2
// 222.092 us; speedup vs baseline: 1.7622x; 1.7622x over previous
//
#include <hip/hip_runtime.h>
#include <hip/hip_bf16.h>

// Problem constants
#define B_ 4
#define S_ 2048
#define D_ 1024
#define H_ 16
#define HD_ 64
#define M_ 8192           // B*S
#define NEGV -1000000.0f
#define CEXP 0.18033688011112042f   // (1/sqrt(HD)) * log2(e) = 0.125 * 1.4426950408889634

typedef __attribute__((ext_vector_type(8))) __bf16 bf16x8;
typedef __attribute__((ext_vector_type(4))) float f32x4;
typedef __attribute__((ext_vector_type(16))) float f32x16;

__device__ __forceinline__ f32x4 mfma16(bf16x8 a, bf16x8 b, f32x4 c) {
  return __builtin_amdgcn_mfma_f32_16x16x32_bf16(a, b, c, 0, 0, 0);
}
__device__ __forceinline__ f32x16 mfma32(bf16x8 a, bf16x8 b, f32x16 c) {
  return __builtin_amdgcn_mfma_f32_32x32x16_bf16(a, b, c, 0, 0, 0);
}

// async global->LDS, 16B per lane. LDS dest is wave-uniform base (HW adds lane*16).
__device__ __forceinline__ void gld_lds16(const __hip_bfloat16* g, __hip_bfloat16* l) {
  __builtin_amdgcn_global_load_lds(
      (const __attribute__((address_space(1))) void*)g,
      (__attribute__((address_space(3))) void*)l, 16, 0, 0);
}

// ---------------- fp32 -> bf16 elementwise convert (vectorized, optional row-skip) ----
__global__ __launch_bounds__(256) void convert_x(const float* __restrict__ X,
                                                 __hip_bfloat16* __restrict__ Y, int n4,
                                                 const int* __restrict__ vskip) {
  int i = blockIdx.x * blockDim.x + threadIdx.x;
  if (i >= n4) return;
  if (vskip) {
    int gm = i >> 8;  // 256 float4 per 1024-wide row
    int vlen = vskip[gm >> 11];
    if (vlen > 0 && (gm & 2047) >= ((vlen + 63) & ~63)) return;  // rows >= ceil64 unused
  }
  float4 v = reinterpret_cast<const float4*>(X)[i];
  union { __hip_bfloat16 h[4]; ushort4 u; } cv;
  cv.h[0] = __float2bfloat16(v.x);
  cv.h[1] = __float2bfloat16(v.y);
  cv.h[2] = __float2bfloat16(v.z);
  cv.h[3] = __float2bfloat16(v.w);
  reinterpret_cast<ushort4*>(Y)[i] = cv.u;
}

// ---------------- W[1024][1024] fp32 -> W^T bf16 ----------------
__global__ __launch_bounds__(256) void convert_wt(const float* __restrict__ W,
                                                  __hip_bfloat16* __restrict__ Wt) {
  __shared__ float tile[32][33];
  int c0 = blockIdx.x * 32, r0 = blockIdx.y * 32;
  int tx = threadIdx.x, ty = threadIdx.y;
#pragma unroll
  for (int rr = ty; rr < 32; rr += 8)
    tile[rr][tx] = W[(size_t)(r0 + rr) * D_ + c0 + tx];
  __syncthreads();
#pragma unroll
  for (int rr = ty; rr < 32; rr += 8)
    Wt[(size_t)(c0 + rr) * D_ + r0 + tx] = __float2bfloat16(tile[tx][rr]);
}

// ---------------- GEMM: C[M,N] = A[M,K] * Bt[N,K]^T  (bf16 in, templated epilogue) ----
// EPI 0: bf16 out scattered to [B][H][S][HD]   (Q, K projections)
// EPI 1: bf16 out scattered to [B][H][HD][S]   (V^T projection)
// EPI 2: fp32 out row-major [M][N]             (final @ Wo)
// vskip != nullptr: skip M-blocks whose rows are all >= ceil64(valid_len[b]) (K/V proj).
template <int EPI>
__global__ __launch_bounds__(256) void gemm_bt(const __hip_bfloat16* __restrict__ A,
                                               const __hip_bfloat16* __restrict__ Bt,
                                               void* __restrict__ Cout,
                                               const int* __restrict__ vskip) {
  const int m0 = blockIdx.x * 128, n0 = blockIdx.y * 128;
  if (vskip) {
    int vlen = vskip[m0 >> 11];
    if (vlen > 0 && (m0 & 2047) >= ((vlen + 63) & ~63)) return;
  }
  const int t = threadIdx.x, lane = t & 63, wid = t >> 6;
  const int lc = lane & 15, g = lane >> 4;
  __shared__ __align__(16) __hip_bfloat16 As[128 * 32];
  __shared__ __align__(16) __hip_bfloat16 Bs[128 * 32];
  f32x4 acc[4][4] = {};
  const int wm = (wid & 1) * 64, wn = (wid >> 1) * 64;
  const int srow = lane >> 2;  // 0..15
  const int sg = lane & 3;     // 16B granule within 64B row

  for (int k0 = 0; k0 < D_; k0 += 32) {
#pragma unroll
    for (int c = 0; c < 2; ++c) {
      int row = c * 64 + wid * 16 + srow;
      gld_lds16(A + (size_t)(m0 + row) * D_ + k0 + sg * 8, As + (c * 64 + wid * 16) * 32);
      gld_lds16(Bt + (size_t)(n0 + row) * D_ + k0 + sg * 8, Bs + (c * 64 + wid * 16) * 32);
    }
    __syncthreads();
    bf16x8 af[4], bf[4];
#pragma unroll
    for (int mi = 0; mi < 4; ++mi)
      af[mi] = *reinterpret_cast<const bf16x8*>(As + (wm + mi * 16 + lc) * 32 + g * 8);
#pragma unroll
    for (int ni = 0; ni < 4; ++ni)
      bf[ni] = *reinterpret_cast<const bf16x8*>(Bs + (wn + ni * 16 + lc) * 32 + g * 8);
#pragma unroll
    for (int mi = 0; mi < 4; ++mi)
#pragma unroll
      for (int ni = 0; ni < 4; ++ni)
        acc[mi][ni] = mfma16(af[mi], bf[ni], acc[mi][ni]);
    __syncthreads();
  }

#pragma unroll
  for (int mi = 0; mi < 4; ++mi) {
#pragma unroll
    for (int ni = 0; ni < 4; ++ni) {
#pragma unroll
      for (int i = 0; i < 4; ++i) {
        int gm = m0 + wm + mi * 16 + g * 4 + i;
        int gn = n0 + wn + ni * 16 + lc;
        float val = acc[mi][ni][i];
        if constexpr (EPI == 0) {
          int b = gm >> 11, s = gm & 2047, h = gn >> 6, d = gn & 63;
          ((__hip_bfloat16*)Cout)[(((size_t)(b * H_ + h) * S_ + s) << 6) + d] =
              __float2bfloat16(val);
        } else if constexpr (EPI == 1) {
          int b = gm >> 11, s = gm & 2047, h = gn >> 6, d = gn & 63;
          ((__hip_bfloat16*)Cout)[(((size_t)(b * H_ + h) * HD_ + d) << 11) + s] =
              __float2bfloat16(val);
        } else {
          ((float*)Cout)[(size_t)gm * D_ + gn] = val;
        }
      }
    }
  }
}

// ---------------- Flash attention, swapped-operand 32x32 MFMA ----------------
// grid: (S/128, B*H), 256 threads = 4 waves, wave owns 32 q-rows.
// S^T = mfma(K, Q): lane's q = lane&31 (one q-row/lane -> scalar m,l, shuffle-free
// softmax except one xor-32). O^T = mfma(V^T, P^T): acc col = q -> scalar rescale.
// KV tiles of 64; tail tiles beyond ceil64(vlen) contribute 0 -> skipped.
// All LDS tiles use the 16B/8B-granule XOR swizzle verified conflict-free in R0.
__global__ __launch_bounds__(256) void attn(const __hip_bfloat16* __restrict__ Qh,
                                            const __hip_bfloat16* __restrict__ Kh,
                                            const __hip_bfloat16* __restrict__ Vt,
                                            const int* __restrict__ vlens,
                                            __hip_bfloat16* __restrict__ O) {
  const int qt = blockIdx.x, bh = blockIdx.y;
  const int b = bh >> 4, h = bh & 15;
  const int t = threadIdx.x, lane = t & 63, w = t >> 6;
  const int q = lane & 31;   // q-row owned by this lane (S^T col / O^T col)
  const int hh = lane >> 5;  // half-wave
  const int vlen = vlens[b];

  // single allocation so the epilogue can alias K/V region
  __shared__ __align__(16) __hip_bfloat16 smem[4096 + 4096 + 4 * 2048];  // 32 KiB
  __hip_bfloat16* Ks = smem;               // [64 keys][64 d]
  __hip_bfloat16* Vs = smem + 4096;        // [64 d][64 keys]
  __hip_bfloat16* Pw = smem + 8192 + w * 2048;  // per-wave P [32 q][64 keys]

  const __hip_bfloat16* Qb = Qh + (size_t)bh * S_ * HD_;
  const __hip_bfloat16* Kb = Kh + (size_t)bh * S_ * HD_;
  const __hip_bfloat16* Vb = Vt + (size_t)bh * HD_ * S_;

  const int q0 = qt * 128 + w * 32;
  const int qrow = q0 + q;
  bf16x8 qf[4];
#pragma unroll
  for (int kk = 0; kk < 4; ++kk)
    qf[kk] = *reinterpret_cast<const bf16x8*>(Qb + (size_t)qrow * HD_ + kk * 16 + hh * 8);

  f32x16 accT[2] = {};  // O^T: accT[ctd] reg r -> d = ctd*32+(r&3)+8*(r>>2)+4*hh, col=q
  float m_i = -__builtin_inff(), l_i = 0.f;

  const int srow = lane >> 3;  // 0..7
  const int sg = lane & 7;     // 16B granule in 128B row

  const int kv_end = (vlen == 0) ? S_ : min(S_, (vlen + 63) & ~63);

  for (int kv = 0; kv < kv_end; kv += 64) {
    // stage K [64][64] and V^T [64][64], source pre-swizzled (granule16 ^= row&7)
#pragma unroll
    for (int c = 0; c < 2; ++c) {
      int r = w * 16 + c * 8 + srow;
      int gs = sg ^ (r & 7);
      gld_lds16(Kb + (size_t)(kv + r) * HD_ + gs * 8, Ks + (w * 16 + c * 8) * 64);
      gld_lds16(Vb + (size_t)r * S_ + kv + gs * 8, Vs + (w * 16 + c * 8) * 64);
    }
    __syncthreads();

    // S^T tiles: sc[ct] covers keys ct*32.., col = q
    f32x16 sc[2];
#pragma unroll
    for (int ct = 0; ct < 2; ++ct) {
      f32x16 a = {};
#pragma unroll
      for (int kk = 0; kk < 4; ++kk) {
        int row = ct * 32 + q;
        bf16x8 kf = *reinterpret_cast<const bf16x8*>(
            Ks + row * 64 + (((kk * 2 + hh) ^ (row & 7)) << 3));
        a = mfma32(kf, qf[kk], a);
      }
      sc[ct] = a;
    }

    // padding mask (boundary tile only; wave-uniform branch)
    if (kv + 64 > vlen) {
#pragma unroll
      for (int ct = 0; ct < 2; ++ct)
#pragma unroll
        for (int r = 0; r < 16; ++r) {
          int j = kv + ct * 32 + (r & 3) + 8 * (r >> 2) + 4 * hh;
          if (j >= vlen) sc[ct][r] = NEGV;
        }
    }

    // online softmax: in-lane max + one xor-32
    float pm = sc[0][0];
#pragma unroll
    for (int r = 1; r < 16; ++r) pm = fmaxf(pm, sc[0][r]);
#pragma unroll
    for (int r = 0; r < 16; ++r) pm = fmaxf(pm, sc[1][r]);
    pm = fmaxf(pm, __shfl_xor(pm, 32));

    // defer-max (T13): raw-score threshold 64 = 8 / 0.125 scale
    if (!__all(pm <= m_i + 64.f)) {
      float mn = fmaxf(m_i, pm);
      float al = exp2f((m_i - mn) * CEXP);
      m_i = mn;
      l_i *= al;
#pragma unroll
      for (int ctd = 0; ctd < 2; ++ctd)
#pragma unroll
        for (int r = 0; r < 16; ++r) accT[ctd][r] *= al;
    }

    // exp + pack + P-store fused (b64 writes, 8B-granule XOR swizzle)
    float mC = m_i * CEXP;
    float rs = 0.f;
#pragma unroll
    for (int ct = 0; ct < 2; ++ct)
#pragma unroll
      for (int a2 = 0; a2 < 4; ++a2) {
        union { __hip_bfloat16 hx[4]; ushort4 u4; } pk;
#pragma unroll
        for (int e = 0; e < 4; ++e) {
          float pe = exp2f(fmaf(sc[ct][a2 * 4 + e], CEXP, -mC));
          rs += pe;
          pk.hx[e] = __float2bfloat16(pe);
        }
        int gs8 = (ct * 8 + a2 * 2 + hh) ^ ((q & 7) << 1);
        *reinterpret_cast<ushort4*>(Pw + q * 64 + gs8 * 4) = pk.u4;
      }
    rs += __shfl_xor(rs, 32);
    l_i += rs;

    // O^T += mfma(V^T, P^T): per-wave P, no barrier needed (same-wave RAW via lgkmcnt)
#pragma unroll
    for (int kk = 0; kk < 4; ++kk) {
      bf16x8 pf = *reinterpret_cast<const bf16x8*>(
          Pw + q * 64 + (((kk * 4 + hh * 2) ^ ((q & 7) << 1)) << 2));
#pragma unroll
      for (int ctd = 0; ctd < 2; ++ctd) {
        int vr = ctd * 32 + q;
        bf16x8 vf = *reinterpret_cast<const bf16x8*>(
            Vs + vr * 64 + (((kk * 2 + hh) ^ (vr & 7)) << 3));
        accT[ctd] = mfma32(vf, pf, accT[ctd]);
      }
    }
    __syncthreads();
  }

  // epilogue: O^T -> O via per-wave LDS transpose (reuse K/V region), coalesced stores
  float inv = 1.f / l_i;
  __hip_bfloat16* Ot = smem + w * 2048;  // [32 q][64 d], 8B-granule swizzle
#pragma unroll
  for (int ctd = 0; ctd < 2; ++ctd)
#pragma unroll
    for (int a2 = 0; a2 < 4; ++a2) {
      union { __hip_bfloat16 hx[4]; ushort4 u4; } pk;
#pragma unroll
      for (int e = 0; e < 4; ++e)
        pk.hx[e] = __float2bfloat16(accT[ctd][a2 * 4 + e] * inv);
      int gs8 = (ctd * 8 + a2 * 2 + hh) ^ ((q & 7) << 1);  // = d/4 swizzled
      *reinterpret_cast<ushort4*>(Ot + q * 64 + gs8 * 4) = pk.u4;
    }
  // read rows (own wave region, same-wave ordering) and store 16B coalesced
#pragma unroll
  for (int rr = 0; rr < 4; ++rr) {
    int row = rr * 8 + (lane >> 3);  // q-row within wave tile
    int c16 = lane & 7;              // 16B chunk of d
    float4 v4 = *reinterpret_cast<const float4*>(
        Ot + row * 64 + (((c16 * 2) ^ ((row & 7) << 1)) << 2));
    int s = qt * 128 + w * 32 + row;
    *reinterpret_cast<float4*>(O + ((size_t)b * S_ + s) * D_ + h * HD_ + c16 * 8) = v4;
  }
}

extern "C" void kernel_launch(void* const* d_in, const int* in_sizes, int n_in,
                              void* d_out, int out_size, void* d_ws, size_t ws_size,
                              hipStream_t stream) {
  const float* Xq = (const float*)d_in[0];
  const float* Xk = (const float*)d_in[1];
  const float* Xv = (const float*)d_in[2];
  const int* vl = (const int*)d_in[3];
  const float* Wq = (const float*)d_in[4];
  const float* Wk = (const float*)d_in[5];
  const float* Wv = (const float*)d_in[6];
  const float* Wo = (const float*)d_in[7];
  float* out = (float*)d_out;

  char* ws = (char*)d_ws;
  const size_t XB = (size_t)M_ * D_ * 2;   // 16 MB bf16 [8192][1024]
  const size_t WB = (size_t)D_ * D_ * 2;   // 2 MB bf16 [1024][1024]
  __hip_bfloat16* xb = (__hip_bfloat16*)(ws);                 // X bf16 (reused), later O
  __hip_bfloat16* wtq = (__hip_bfloat16*)(ws + XB);
  __hip_bfloat16* wtk = (__hip_bfloat16*)(ws + XB + WB);
  __hip_bfloat16* wtv = (__hip_bfloat16*)(ws + XB + 2 * WB);
  __hip_bfloat16* wto = (__hip_bfloat16*)(ws + XB + 3 * WB);
  __hip_bfloat16* Qh = (__hip_bfloat16*)(ws + XB + 4 * WB);      // [B][H][S][HD]
  __hip_bfloat16* Kh = (__hip_bfloat16*)(ws + 2 * XB + 4 * WB);  // [B][H][S][HD]
  __hip_bfloat16* Vh = (__hip_bfloat16*)(ws + 3 * XB + 4 * WB);  // [B][H][HD][S]
  __hip_bfloat16* Obuf = xb;  // alias: X buffer dead after V projection

  dim3 tg(32, 32), tb(32, 8);
  convert_wt<<<tg, tb, 0, stream>>>(Wq, wtq);
  convert_wt<<<tg, tb, 0, stream>>>(Wk, wtk);
  convert_wt<<<tg, tb, 0, stream>>>(Wv, wtv);
  convert_wt<<<tg, tb, 0, stream>>>(Wo, wto);

  const int n4 = M_ * D_ / 4;
  dim3 gg(M_ / 128, D_ / 128);
  convert_x<<<n4 / 256, 256, 0, stream>>>(Xq, xb, n4, nullptr);
  gemm_bt<0><<<gg, 256, 0, stream>>>(xb, wtq, Qh, nullptr);
  convert_x<<<n4 / 256, 256, 0, stream>>>(Xk, xb, n4, vl);
  gemm_bt<0><<<gg, 256, 0, stream>>>(xb, wtk, Kh, vl);
  convert_x<<<n4 / 256, 256, 0, stream>>>(Xv, xb, n4, vl);
  gemm_bt<1><<<gg, 256, 0, stream>>>(xb, wtv, Vh, vl);

  attn<<<dim3(S_ / 128, B_ * H_), 256, 0, stream>>>(Qh, Kh, Vh, vl, Obuf);
  gemm_bt<2><<<gg, 256, 0, stream>>>(Obuf, wto, out, nullptr);
}